// Round 13
// baseline (62.273 us; speedup 1.0000x reference)
//
#include <hip/hip_runtime.h>
#include <math.h>

#define Lc 128
#define Rc 1024
#define Pc 8
#define Ec 64
#define Fc 64

// exp(-((d-mu)/sigma)^2) = exp2(-(C*(d-mu))^2), C = (1/0.15625)*sqrt(log2(e))
#define CSCALE   7.68718341623328f
#define MU_STEP  0.15873015873015873f   // 10/63
#define MUC      (MU_STEP * CSCALE)

#define NBLKM 1024   // ff_mfma blocks: 16 ng x 8 mt x 8 ez  (4 blocks/CU)

typedef __attribute__((ext_vector_type(8))) short short8;   // 8 bf16 (4 VGPRs)
typedef __attribute__((ext_vector_type(4))) float f32x4;

__device__ __forceinline__ unsigned short bf16_rn(float x) {
    unsigned int u = __float_as_uint(x);
    u += 0x7FFF + ((u >> 16) & 1);
    return (unsigned short)(u >> 16);
}
__device__ __forceinline__ float bf16_f32(unsigned short b) {
    return __uint_as_float(((unsigned int)b) << 16);
}

#define N4_LIG (Lc * Ec * Fc / 4)   // 131072
#define N4_REC (Rc * Ec * Fc / 4)   // 1048576

// ---- split-convert BOTH tensors f32 -> (hi,lo) bf16, [g=row*64+e][hi 0..63 | lo 64..127]
__global__ __launch_bounds__(256)
void ff_cvt(const float* __restrict__ lig_feat, const float* __restrict__ rec_feat,
            unsigned short* __restrict__ ligP, unsigned short* __restrict__ recP)
{
    int i = blockIdx.x * 256 + threadIdx.x;
    const float* src;
    unsigned short* dst;
    int idx;
    if (i < N4_LIG) { src = lig_feat; dst = ligP; idx = i; }
    else            { src = rec_feat; dst = recP; idx = i - N4_LIG; }
    float4 v = ((const float4*)src)[idx];
    int s0 = idx * 4;
    size_t g = (size_t)(s0 >> 6);
    int kb = s0 & 63;
    ushort4 h, l;
    h.x = bf16_rn(v.x); l.x = bf16_rn(v.x - bf16_f32(h.x));
    h.y = bf16_rn(v.y); l.y = bf16_rn(v.y - bf16_f32(h.y));
    h.z = bf16_rn(v.z); l.z = bf16_rn(v.z - bf16_f32(h.z));
    h.w = bf16_rn(v.w); l.w = bf16_rn(v.w - bf16_f32(h.w));
    *(ushort4*)(dst + g * 128 + kb)      = h;
    *(ushort4*)(dst + g * 128 + 64 + kb) = l;
}

// ---- fused: per (16l x 16r) C-tile, per e: 6 split-MFMAs -> fold exp2 into us[p] ----
// Low-pressure variant: NO prefetch double-buffer (frag state 32 regs, total ~85 live);
// latency hidden by 4 blocks/CU TLP. 32 KB LDS keeps compiler-visible occupancy at
// 5 blocks/CU -> ~102-reg target > demand -> no spill.
__global__ __launch_bounds__(256, 4)
void ff_mfma(const unsigned short* __restrict__ ligP,
             const unsigned short* __restrict__ recP,
             const float* __restrict__ lig_coords,
             const float* __restrict__ rec_coords,
             float* __restrict__ partial)
{
    __shared__ float wred[8192];   // 32 KB; low words = cross-wave reduce scratch

    const int tid  = threadIdx.x;
    const int lane = tid & 63;
    const int w    = tid >> 6;
    const int n16  = lane & 15;
    const int kg   = lane >> 4;

    // bid&7 = XCD: each XCD owns 2 n-groups (128 rec rows, 2 MB recP slice, L2-resident)
    const int bid = blockIdx.x;
    const int loc = bid >> 3;
    const int ng  = (bid & 7) * 2 + (loc & 1);
    const int mt  = (loc >> 1) & 7;
    const int ez  = loc >> 4;              // 0..7
    const int nt  = ng * 4 + w;
    const int r   = nt * 16 + n16;
    const int e0  = ez * 8;

    const float rcx = rec_coords[r * 3 + 0];
    const float rcy = rec_coords[r * 3 + 1];
    const float rcz = rec_coords[r * 3 + 2];
    float dsc[Pc][4];
    #pragma unroll
    for (int reg = 0; reg < 4; ++reg) {
        const int l = mt * 16 + kg * 4 + reg;
        #pragma unroll
        for (int p = 0; p < Pc; ++p) {
            const float* lcp = lig_coords + ((size_t)p * Lc + l) * 3;
            float dx = lcp[0] - rcx;
            float dy = lcp[1] - rcy;
            float dz = lcp[2] - rcz;
            dsc[p][reg] = sqrtf(dx * dx + dy * dy + dz * dz) * CSCALE;
        }
    }

    const unsigned short* ap = ligP + ((size_t)(mt * 16 + n16) * Ec + e0) * 128 + kg * 8;
    const unsigned short* bp = recP + ((size_t)r * Ec + e0) * 128 + kg * 8;

    float us[Pc];
    #pragma unroll
    for (int p = 0; p < Pc; ++p) us[p] = 0.f;

    for (int te = 0; te < 8; ++te) {
        const unsigned short* a = ap + (size_t)te * 128;
        const unsigned short* b = bp + (size_t)te * 128;
        short8 Ah0 = *(const short8*)(a);
        short8 Ah1 = *(const short8*)(a + 32);
        short8 Al0 = *(const short8*)(a + 64);
        short8 Al1 = *(const short8*)(a + 96);
        short8 Bh0 = *(const short8*)(b);
        short8 Bh1 = *(const short8*)(b + 32);
        short8 Bl0 = *(const short8*)(b + 64);
        short8 Bl1 = *(const short8*)(b + 96);

        // atn tile for this e: hh + al*bh + ah*bl (drop al*bl, ~2^-18 rel)
        f32x4 acc = {0.f, 0.f, 0.f, 0.f};
        acc = __builtin_amdgcn_mfma_f32_16x16x32_bf16(Ah0, Bh0, acc, 0, 0, 0);
        acc = __builtin_amdgcn_mfma_f32_16x16x32_bf16(Ah1, Bh1, acc, 0, 0, 0);
        acc = __builtin_amdgcn_mfma_f32_16x16x32_bf16(Al0, Bh0, acc, 0, 0, 0);
        acc = __builtin_amdgcn_mfma_f32_16x16x32_bf16(Al1, Bh1, acc, 0, 0, 0);
        acc = __builtin_amdgcn_mfma_f32_16x16x32_bf16(Ah0, Bl0, acc, 0, 0, 0);
        acc = __builtin_amdgcn_mfma_f32_16x16x32_bf16(Ah1, Bl1, acc, 0, 0, 0);

        const float musC = (float)(e0 + te) * MUC;
        #pragma unroll
        for (int reg = 0; reg < 4; ++reg) {
            const float av = acc[reg];
            #pragma unroll
            for (int p = 0; p < Pc; ++p) {
                const float t = dsc[p][reg] - musC;
                us[p] = fmaf(av, __builtin_amdgcn_exp2f(-(t * t)), us[p]);
            }
        }
    }

    // butterfly over 64 lanes, then across the 4 waves
    #pragma unroll
    for (int p = 0; p < Pc; ++p) {
        float v = us[p];
        #pragma unroll
        for (int off = 32; off >= 1; off >>= 1)
            v += __shfl_xor(v, off, 64);
        us[p] = v;
    }
    if (lane == 0) {
        #pragma unroll
        for (int p = 0; p < Pc; ++p) wred[w * Pc + p] = us[p];
    }
    __syncthreads();
    if (tid < Pc) {
        float s = 0.f;
        #pragma unroll
        for (int k = 0; k < 4; ++k) s += wred[k * Pc + tid];
        partial[(size_t)bid * Pc + tid] = s;
    }
}

// reduce NBLKM block-partials x 8 poses -> 8 outputs
__global__ void ff_reduce(const float* __restrict__ partial, float* __restrict__ out)
{
    const int w    = threadIdx.x >> 6;
    const int lane = threadIdx.x & 63;
    float v = 0.f;
    #pragma unroll
    for (int j = 0; j < NBLKM / 64; ++j)
        v += partial[(size_t)(lane + 64 * j) * Pc + w];
    #pragma unroll
    for (int off = 32; off >= 1; off >>= 1)
        v += __shfl_xor(v, off, 64);
    if (lane == 0) out[w] = 0.1f * v;
}

extern "C" void kernel_launch(void* const* d_in, const int* in_sizes, int n_in,
                              void* d_out, int out_size, void* d_ws, size_t ws_size,
                              hipStream_t stream)
{
    const float* lig_feat   = (const float*)d_in[0];
    const float* rec_feat   = (const float*)d_in[1];
    const float* lig_coords = (const float*)d_in[2];
    const float* rec_coords = (const float*)d_in[3];
    float* out = (float*)d_out;

    float*          partial = (float*)d_ws;                                   // 32 KB
    unsigned short* ligP    = (unsigned short*)((char*)d_ws + 65536);         // 2 MB
    unsigned short* recP    = (unsigned short*)((char*)d_ws + 65536 + (2u << 20)); // 16 MB

    ff_cvt<<<(N4_LIG + N4_REC) / 256, 256, 0, stream>>>(lig_feat, rec_feat, ligP, recP);
    ff_mfma<<<NBLKM, 256, 0, stream>>>(ligP, recP, lig_coords, rec_coords, partial);
    ff_reduce<<<1, 512, 0, stream>>>(partial, out);
}